// Round 3
// baseline (131.009 us; speedup 1.0000x reference)
//
#include <hip/hip_runtime.h>
#include <hip/hip_bf16.h>
#include <math.h>

#define EPS 1e-8f

typedef __attribute__((ext_vector_type(8))) short short8;
typedef __attribute__((ext_vector_type(16))) float floatx16;
typedef unsigned short ushort_t;

#define GPTR(p) ((const __attribute__((address_space(1))) void*)(p))
#define LPTR(p) ((__attribute__((address_space(3))) void*)(p))

__device__ __forceinline__ unsigned short f2bf(float f) {
  unsigned int u = __float_as_uint(f);
  u += 0x7FFFu + ((u >> 16) & 1u);   // RNE
  return (unsigned short)(u >> 16);
}

// ---------------- kA: per-speaker column sums -> sums_bf, ss, rcn ----------
__global__ __launch_bounds__(256) void kA(const float* __restrict__ x,
    ushort_t* __restrict__ sums_bf, float* __restrict__ ss,
    float* __restrict__ rcn, const float* __restrict__ wp) {
  const int n = blockIdx.x;
  const int t = threadIdx.x;
  const float* xp = x + (size_t)n * (64 * 768);
  float s0 = 0.f, s1 = 0.f, s2 = 0.f;
#pragma unroll 8
  for (int m = 0; m < 64; ++m) {
    const float* r = xp + m * 768;
    s0 += r[t]; s1 += r[t + 256]; s2 += r[t + 512];
  }
  ushort_t* sb = sums_bf + (size_t)n * 768;
  sb[t] = f2bf(s0); sb[t + 256] = f2bf(s1); sb[t + 512] = f2bf(s2);
  float lss = s0 * s0 + s1 * s1 + s2 * s2;
  for (int o = 32; o; o >>= 1) lss += __shfl_xor(lss, o, 64);
  __shared__ float red[4];
  if ((t & 63) == 0) red[t >> 6] = lss;
  __syncthreads();
  if (t == 0) {
    const float v = red[0] + red[1] + red[2] + red[3];
    ss[n] = v;
    rcn[n] = (*wp) / fmaxf(sqrtf(v), 64.f * EPS);  // w / (M * cn)
  }
}

// ---------------- kC: fused GEMM(32x32x16) + softmax-denominator + loss ----
// 512 blocks x 128 thr (2 waves x 32 j). A (sums_bf) staged frag-major in
// LDS via global_load_lds (linear dest, per-lane source). B (x) in regs.
__global__ __launch_bounds__(128, 1) void kC(const float* __restrict__ x,
    const ushort_t* __restrict__ sums_bf, const float* __restrict__ rcn,
    const float* __restrict__ ss, const float* __restrict__ wp,
    const float* __restrict__ bp, float* __restrict__ out) {
  __shared__ ushort_t Abuf[2][12288];   // 2 x 24KB, frag-major
  const int t = threadIdx.x;
  const int wv = t >> 6;
  const int l = t & 63;
  const int hi = l >> 5;
  const int jw0 = blockIdx.x * 64 + wv * 32;
  const int jcol = jw0 + (l & 31);
  const int i0 = jw0 >> 6;              // speaker index (wave-uniform)

// stage 12 frags (this wave's share of 24) for half-K tile (NT_,KH_) -> buf BUF_
#define STAGE(KH_, BUF_, NT_)                                                  \
  if ((NT_) < 16) {                                                            \
    const ushort_t* gb = sums_bf + (size_t)((NT_) * 32 + (l & 31)) * 768 +     \
                         (KH_) * 384 + hi * 8;                                 \
    _Pragma("unroll")                                                          \
    for (int i_ = 0; i_ < 12; ++i_) {                                          \
      const int fi_ = wv * 12 + i_;                                            \
      __builtin_amdgcn_global_load_lds(GPTR(gb + fi_ * 16),                    \
                                       LPTR(&Abuf[BUF_][fi_ * 512]), 16, 0, 0);\
    }                                                                          \
  }

#define COMPUTE(KH_, BUF_)                                                     \
  _Pragma("unroll")                                                            \
  for (int i_ = 0; i_ < 24; ++i_) {                                            \
    short8 af_ = *(const short8*)&Abuf[BUF_][(i_ * 64 + l) * 8];               \
    acc = __builtin_amdgcn_mfma_f32_32x32x16_bf16(af_, bfr[(KH_) * 24 + i_],   \
                                                  acc, 0, 0, 0);              \
  }

  // issue first stage before the B prologue so L2 latency hides under it
  STAGE(0, 0, 0)

  // ---- B prologue: x rows -> bf16 frags; row norm xx in fp32
  short8 bfr[48];
  float xx2 = 0.f;
  {
    const float* xrow = x + (size_t)jcol * 768;
#pragma unroll
    for (int kk = 0; kk < 48; ++kk) {
      const float* p = xrow + kk * 16 + hi * 8;
      float4 u0 = *(const float4*)p;
      float4 u1 = *(const float4*)(p + 4);
      xx2 += u0.x * u0.x + u0.y * u0.y + u0.z * u0.z + u0.w * u0.w
           + u1.x * u1.x + u1.y * u1.y + u1.z * u1.z + u1.w * u1.w;
      short8 r;
      r[0] = (short)f2bf(u0.x); r[1] = (short)f2bf(u0.y);
      r[2] = (short)f2bf(u0.z); r[3] = (short)f2bf(u0.w);
      r[4] = (short)f2bf(u1.x); r[5] = (short)f2bf(u1.y);
      r[6] = (short)f2bf(u1.z); r[7] = (short)f2bf(u1.w);
      bfr[kk] = r;
    }
  }
  const float xx_tot = xx2 + __shfl_xor(xx2, 32, 64);
  const float xn = fmaxf(sqrtf(xx_tot), EPS);
  const float rx = 1.f / xn;
  const float ww = *wp, bb = *bp;

  floatx16 acc;
#pragma unroll
  for (int r = 0; r < 16; ++r) acc[r] = 0.f;
  float colp = 0.f;
  float sxl = 0.f;

  for (int nt = 0; nt < 16; ++nt) {
    __syncthreads();                 // buf0 (nt,0) ready; buf1 free
    STAGE(1, 1, nt)
    COMPUTE(0, 0)
    __syncthreads();                 // buf1 (nt,1) ready; buf0 free
    STAGE(0, 0, nt + 1)
    COMPUTE(1, 1)

    // epilogue for n-tile nt: S = acc * rcn[n] * rx + b
    {
      const float* rc = rcn + nt * 32;
#pragma unroll
      for (int r = 0; r < 16; ++r) {
        const int row = (r & 3) + 8 * (r >> 2) + 4 * hi;
        const float s = acc[r] * rc[row] * rx + bb;
        colp += __expf(s);
      }
      if (nt == (i0 >> 5)) {         // diagonal block: capture sx = dot(sums_i, x_j)
        const int r0 = i0 & 31;
        const int tgt_hi = (r0 >> 2) & 1;
        const int tgt_r = 4 * (r0 >> 3) + (r0 & 3);
        float sxv = 0.f;
#pragma unroll
        for (int r = 0; r < 16; ++r) if (r == tgt_r) sxv = acc[r];
        const float o = __shfl_xor(sxv, 32, 64);
        sxl = (hi == tgt_hi) ? sxv : o;
      }
#pragma unroll
      for (int r = 0; r < 16; ++r) acc[r] = 0.f;
    }
  }

  // ---- fused loss tail (block owns its 64 j-columns over all n)
  colp += __shfl_xor(colp, 32, 64);  // full column sum over 512 n

  const float ssi = ss[i0];
  const float rci = rcn[i0];
  const float sd = sxl * rci * rx + bb;                       // S_diag
  const float exn = sqrtf(fmaxf(ssi - 2.f * sxl + xx_tot, 0.f)) / 63.f;
  const float edot = (sxl - xx_tot) / 63.f;
  const float sm = ww * edot / (fmaxf(exn, EPS) * xn) + bb;   // S_same
  const float tot = colp - __expf(sd) + __expf(sm);
  float L = -sm + logf(fmaxf(tot, 1e-30f));
  L = hi ? 0.f : L;
  for (int o = 32; o; o >>= 1) L += __shfl_xor(L, o, 64);

  __syncthreads();                   // done with Abuf; reuse as scratch
  float* redf = (float*)&Abuf[0][0];
  if (l == 0) redf[wv] = L;
  __syncthreads();
  if (t == 0) atomicAdd(out, redf[0] + redf[1]);
}

extern "C" void kernel_launch(void* const* d_in, const int* in_sizes, int n_in,
                              void* d_out, int out_size, void* d_ws, size_t ws_size,
                              hipStream_t stream) {
  const float* x  = (const float*)d_in[0];
  const float* wp = (const float*)d_in[1];
  const float* bp = (const float*)d_in[2];
  float* out = (float*)d_out;

  ushort_t* sums_bf = (ushort_t*)d_ws;
  float* ss  = (float*)d_ws + 196608;
  float* rcn = (float*)d_ws + 197120;

  hipMemsetAsync(out, 0, sizeof(float), stream);
  kA<<<512, 256, 0, stream>>>(x, sums_bf, ss, rcn, wp);
  kC<<<512, 128, 0, stream>>>(x, sums_bf, rcn, ss, wp, bp, out);
}